// Round 6
// baseline (211.644 us; speedup 1.0000x reference)
//
#include <hip/hip_runtime.h>
#include <hip/hip_bf16.h>

#define WB 8192
#define WD 128
#define WC 100
#define NSPLIT 64
#define JSPL (WB/NSPLIT)   // 128 j per split
#define NTT (JSPL/16)      // 8 j-steps of 16 rows
#define NCS 64             // class-sum blocks (128 rows each)

typedef __attribute__((ext_vector_type(8))) short short8v;
typedef __attribute__((ext_vector_type(4))) float float4v;

#define SQS 3.798282f                 // sqrt((1/TAU)/ln2): fold scale into bf16 z
#define LN2F 0.69314718055994531f

#define EXP2(x) __builtin_amdgcn_exp2f(x)
#define LOG2(x) __builtin_amdgcn_logf(x)

// ---- workspace layout (bytes) ----
#define WS_ZBF   0u          // bf16 z (pre-scaled): 2097152
#define WS_S     2097152u    // S[100][128] f32 = 51200
#define WS_CNT   2148352u    // cnt[128] int
#define WS_ACC   2148864u    // accf(f32), accn(i32), ticket(i32)
#define WS_PART  2149120u    // part[64][8192] float2 = 4194304

__device__ __forceinline__ unsigned short f2bf(float x){
  unsigned u = __float_as_uint(x);
  u += 0x7fffu + ((u>>16)&1u);      // RNE
  return (unsigned short)(u>>16);
}

__global__ __launch_bounds__(256) void k_zero(float* S, int* cnt,
                                              float* accf, int* accn, int* ticket){
  const int t = threadIdx.x;
  for (int i = t; i < WC*WD; i += 256) S[i] = 0.f;
  if (t < 128) cnt[t] = 0;
  if (t == 0){ accf[0] = 0.f; accn[0] = 0; ticket[0] = 0; }
}

// blocks 0..511: convert+prescale z->bf16; 512..575: class sums (direct atomics)
__global__ __launch_bounds__(256) void k_prep(const float* __restrict__ z,
                                              const int* __restrict__ labels,
                                              unsigned short* __restrict__ zbf,
                                              float* __restrict__ S,
                                              int* __restrict__ cnt){
  __shared__ float sacc[WC*WD];
  __shared__ int slab[128];
  __shared__ int slcnt[WC];
  const int bid = blockIdx.x, t = threadIdx.x;
  if (bid < 512){
    int idx = bid*256 + t;
    const float4* zi = (const float4*)z;
    float4 a = zi[idx*2], b = zi[idx*2+1];
    uint4 o;
    o.x = (unsigned)f2bf(a.x*SQS) | ((unsigned)f2bf(a.y*SQS)<<16);
    o.y = (unsigned)f2bf(a.z*SQS) | ((unsigned)f2bf(a.w*SQS)<<16);
    o.z = (unsigned)f2bf(b.x*SQS) | ((unsigned)f2bf(b.y*SQS)<<16);
    o.w = (unsigned)f2bf(b.z*SQS) | ((unsigned)f2bf(b.w*SQS)<<16);
    ((uint4*)zbf)[idx] = o;
    return;
  }
  const int cb = bid - 512;
  const int rowBase = cb*128;
  for (int i = t; i < WC*WD; i += 256) sacc[i] = 0.f;
  if (t < WC) slcnt[t] = 0;
  if (t < 128) slab[t] = labels[rowBase + t];
  __syncthreads();
  const int col = t & 127, half = t >> 7;
  #pragma unroll 4
  for (int r = 0; r < 64; r++){
    int row = half*64 + r;
    atomicAdd(&sacc[slab[row]*WD + col], z[(size_t)(rowBase+row)*WD + col]);
  }
  if (t < 128) atomicAdd(&slcnt[slab[t]], 1);
  __syncthreads();
  for (int i = t; i < WC*WD; i += 256){
    int c = i >> 7;
    if (slcnt[c] > 0) atomicAdd(&S[i], sacc[i]);
  }
  if (t < WC && slcnt[t] > 0) atomicAdd(&cnt[t], slcnt[t]);
}

// single-pass online-softmax LSE. 1D grid 2048: ablk=bid>>6, split=bid&63.
// wave owns 64 anchors (4 ss of 16); 2 striped (m,l) chains per ss.
__global__ __launch_bounds__(256, 5) void k_lse(const unsigned short* __restrict__ zbf,
                                                float2* __restrict__ part){
  const int t = threadIdx.x;
  const int wv = t>>6, lane = t&63;
  const int awave = (blockIdx.x>>6)*256 + wv*64;
  const int split = blockIdx.x & 63;
  const int j0 = split*JSPL;
  const int lg = lane>>4, ln = lane&15;

  // anchor B-fragments: B[k][n]; lane: n=ln, k=kk*32+lg*8+e
  short8v bf[4][4];
  #pragma unroll
  for (int ss = 0; ss < 4; ss++){
    const unsigned short* zr = zbf + (size_t)(awave + ss*16 + ln)*WD;
    #pragma unroll
    for (int kk = 0; kk < 4; kk++)
      bf[ss][kk] = *(const short8v*)(zr + kk*32 + lg*8);
  }

  float m[4][2], l[4][2];
  #pragma unroll
  for (int ss = 0; ss < 4; ss++){
    m[ss][0] = -INFINITY; m[ss][1] = -INFINITY;
    l[ss][0] = 0.f;       l[ss][1] = 0.f;
  }

  const unsigned short* ap = zbf + (size_t)(j0+ln)*WD + lg*8;
  short8v afA[4], afB[4];
#define LOADA(dst, tt) { const unsigned short* p_ = ap + (size_t)(tt)*16*WD; \
    dst[0] = *(const short8v*)(p_);      dst[1] = *(const short8v*)(p_+32);  \
    dst[2] = *(const short8v*)(p_+64);   dst[3] = *(const short8v*)(p_+96); }

#define COMPUTE(af, tt, str) { \
    const int jb = j0 + (tt)*16; \
    _Pragma("unroll") \
    for (int ss = 0; ss < 4; ss++){ \
      float4v acc = {0.f,0.f,0.f,0.f}; \
      __builtin_amdgcn_s_setprio(1); \
      _Pragma("unroll") \
      for (int kk = 0; kk < 4; kk++) \
        acc = __builtin_amdgcn_mfma_f32_16x16x32_bf16(af[kk], bf[ss][kk], acc, 0,0,0); \
      __builtin_amdgcn_s_setprio(0); \
      float v0 = acc[0], v1 = acc[1], v2 = acc[2], v3 = acc[3]; \
      if (jb == awave + ss*16){ \
        int r0 = lg*4; \
        if (r0+0 == ln) v0 = -INFINITY; \
        if (r0+1 == ln) v1 = -INFINITY; \
        if (r0+2 == ln) v2 = -INFINITY; \
        if (r0+3 == ln) v3 = -INFINITY; \
      } \
      float tmax = fmaxf(fmaxf(v0,v1), fmaxf(v2,v3)); \
      float mn = fmaxf(m[ss][str], tmax); \
      l[ss][str] = l[ss][str]*EXP2(m[ss][str]-mn) \
            + ((EXP2(v0-mn) + EXP2(v1-mn)) + (EXP2(v2-mn) + EXP2(v3-mn))); \
      m[ss][str] = mn; \
    } }

  LOADA(afA, 0);
  for (int tt = 0; tt < NTT; tt += 2){
    LOADA(afB, tt+1);
    COMPUTE(afA, tt, 0);
    if (tt+2 < NTT) LOADA(afA, tt+2);
    COMPUTE(afB, tt+1, 1);
  }
#undef LOADA
#undef COMPUTE

  // merge stripes, then combine lanes {x^16, x^32} (same anchor)
  #pragma unroll
  for (int ss = 0; ss < 4; ss++){
    float mm = fmaxf(m[ss][0], m[ss][1]);
    float ll = l[ss][0]*EXP2(m[ss][0]-mm) + l[ss][1]*EXP2(m[ss][1]-mm);
    #pragma unroll
    for (int off = 16; off < 64; off <<= 1){
      float mo = __shfl_xor(mm, off);
      float lo = __shfl_xor(ll, off);
      float M = fmaxf(mm, mo);
      ll = ll*EXP2(mm-M) + lo*EXP2(mo-M);
      mm = M;
    }
    if (lane < 16)
      part[(size_t)split*WB + awave + ss*16 + lane] = make_float2(mm, ll);
  }
}

__global__ __launch_bounds__(256) void k_final(const float* __restrict__ z,
                                               const int* __restrict__ labels,
                                               const float* __restrict__ S,
                                               const int* __restrict__ cnt,
                                               const float2* __restrict__ part,
                                               float* accf, int* accn, int* ticket,
                                               float* __restrict__ out){
  int i = blockIdx.x*256 + threadIdx.x;
  // pass 1: max over splits
  float mm = -INFINITY;
  #pragma unroll 8
  for (int sp = 0; sp < NSPLIT; sp++)
    mm = fmaxf(mm, part[(size_t)sp*WB + i].x);
  // pass 2: independent exp2 + fma
  float ll = 0.f;
  #pragma unroll 8
  for (int sp = 0; sp < NSPLIT; sp++){
    float2 p = part[(size_t)sp*WB + i];
    ll = fmaf(p.y, EXP2(p.x - mm), ll);
  }
  float lse = (mm + LOG2(ll)) * LN2F;           // natural-log LSE
  int lab = labels[i];
  const float4* zi = (const float4*)(z + (size_t)i*WD);
  const float4* sc = (const float4*)(S + (size_t)lab*WD);
  float pd = 0.f, sd = 0.f;
  #pragma unroll 8
  for (int k = 0; k < WD/4; k++){
    float4 a = zi[k], b = sc[k];
    pd += a.x*b.x + a.y*b.y + a.z*b.z + a.w*b.w;
    sd += a.x*a.x + a.y*a.y + a.z*a.z + a.w*a.w;
  }
  int np = cnt[lab] - 1;
  float loss = 0.f, val = 0.f;
  if (np > 0){ loss = lse - (pd - sd)*10.0f/(float)np; val = 1.f; }
  #pragma unroll
  for (int off = 32; off > 0; off >>= 1){
    loss += __shfl_down(loss, off);
    val  += __shfl_down(val,  off);
  }
  __shared__ float sl[4], sv[4];
  int wv = threadIdx.x>>6, lane = threadIdx.x&63;
  if (lane == 0){ sl[wv] = loss; sv[wv] = val; }
  __syncthreads();
  if (threadIdx.x == 0){
    atomicAdd(accf, sl[0]+sl[1]+sl[2]+sl[3]);
    atomicAdd(accn, (int)(sv[0]+sv[1]+sv[2]+sv[3] + 0.5f));
    __threadfence();
    int tk = atomicAdd(ticket, 1);
    if (tk == (WB/256) - 1){                      // last block finalizes
      float f = atomicAdd(accf, 0.f);
      int   n = atomicAdd(accn, 0);
      out[0] = f / (float)max(n, 1);
    }
  }
}

extern "C" void kernel_launch(void* const* d_in, const int* in_sizes, int n_in,
                              void* d_out, int out_size, void* d_ws, size_t ws_size,
                              hipStream_t stream){
  const float* z = (const float*)d_in[0];
  const int* labels = (const int*)d_in[1];
  char* ws = (char*)d_ws;
  unsigned short* zbf = (unsigned short*)(ws + WS_ZBF);
  float* S      = (float*)(ws + WS_S);
  int*   cnt    = (int*)(ws + WS_CNT);
  float* accf   = (float*)(ws + WS_ACC);
  int*   accn   = (int*)(ws + WS_ACC + 4);
  int*   ticket = (int*)(ws + WS_ACC + 8);
  float2* part  = (float2*)(ws + WS_PART);
  float* out = (float*)d_out;

  hipLaunchKernelGGL(k_zero,  dim3(1),           dim3(256), 0, stream, S, cnt, accf, accn, ticket);
  hipLaunchKernelGGL(k_prep,  dim3(512 + NCS),   dim3(256), 0, stream, z, labels, zbf, S, cnt);
  hipLaunchKernelGGL(k_lse,   dim3(32*NSPLIT),   dim3(256), 0, stream, zbf, part);
  hipLaunchKernelGGL(k_final, dim3(WB/256),      dim3(256), 0, stream,
                     z, labels, S, cnt, part, accf, accn, ticket, out);
}

// Round 7
// 104.523 us; speedup vs baseline: 2.0249x; 2.0249x over previous
//
#include <hip/hip_runtime.h>
#include <hip/hip_bf16.h>

#define WB 8192
#define WD 128
#define WC 100
#define NSPLIT 64
#define JSPL (WB/NSPLIT)   // 128 j per split
#define NTT (JSPL/16)      // 8 j-steps of 16 rows

typedef __attribute__((ext_vector_type(8))) short short8v;
typedef __attribute__((ext_vector_type(4))) float float4v;

#define SQS 3.798282f                 // sqrt((1/TAU)/ln2): fold scale into bf16 z
#define LN2F 0.69314718055994531f

#define EXP2(x) __builtin_amdgcn_exp2f(x)
#define LOG2(x) __builtin_amdgcn_logf(x)

// ---- workspace layout (bytes) ----
#define WS_ZBF   0u          // bf16 z (pre-scaled): 2097152
#define WS_S     2097152u    // S[100][128] f32 = 51200   (memset region starts here)
#define WS_CNT   2148352u    // cnt[128] int = 512
#define WS_ACC   2148864u    // accf(f32), accn(i32), ticket(i32) = 12
#define WS_PART  2149120u    // part[64][8192] float2 = 4194304

__device__ __forceinline__ unsigned short f2bf(float x){
  unsigned u = __float_as_uint(x);
  u += 0x7fffu + ((u>>16)&1u);      // RNE
  return (unsigned short)(u>>16);
}

// blocks 0..511: convert+prescale z->bf16; 512..767: class sums (32 rows each)
__global__ __launch_bounds__(256) void k_prep(const float* __restrict__ z,
                                              const int* __restrict__ labels,
                                              unsigned short* __restrict__ zbf,
                                              float* __restrict__ S,
                                              int* __restrict__ cnt){
  __shared__ float sacc[WC*WD];
  __shared__ int slab[32];
  __shared__ int slcnt[WC];
  const int bid = blockIdx.x, t = threadIdx.x;
  if (bid < 512){
    int idx = bid*256 + t;
    const float4* zi = (const float4*)z;
    float4 a = zi[idx*2], b = zi[idx*2+1];
    uint4 o;
    o.x = (unsigned)f2bf(a.x*SQS) | ((unsigned)f2bf(a.y*SQS)<<16);
    o.y = (unsigned)f2bf(a.z*SQS) | ((unsigned)f2bf(a.w*SQS)<<16);
    o.z = (unsigned)f2bf(b.x*SQS) | ((unsigned)f2bf(b.y*SQS)<<16);
    o.w = (unsigned)f2bf(b.z*SQS) | ((unsigned)f2bf(b.w*SQS)<<16);
    ((uint4*)zbf)[idx] = o;
    return;
  }
  const int cb = bid - 512;           // 256 csum blocks x 32 rows
  const int rowBase = cb*32;
  for (int i = t; i < WC*WD; i += 256) sacc[i] = 0.f;
  if (t < WC) slcnt[t] = 0;
  if (t < 32) slab[t] = labels[rowBase + t];
  __syncthreads();
  const int col = t & 127, half = t >> 7;
  #pragma unroll 4
  for (int r = 0; r < 16; r++){
    int row = r*2 + half;
    atomicAdd(&sacc[slab[row]*WD + col], z[(size_t)(rowBase+row)*WD + col]);
  }
  if (t < 32) atomicAdd(&slcnt[slab[t]], 1);
  __syncthreads();
  for (int i = t; i < WC*WD; i += 256){
    if (slcnt[i>>7] > 0) atomicAdd(&S[i], sacc[i]);
  }
  if (t < WC && slcnt[t] > 0) atomicAdd(&cnt[t], slcnt[t]);
}

// single-pass online-softmax LSE. grid (32 ablk, 64 split) x 256 (4 indep waves).
// wave owns 64 anchors (4 ss of 16); streams 8 j-steps of 16 rows from L2.
__global__ __launch_bounds__(256) void k_lse(const unsigned short* __restrict__ zbf,
                                             float2* __restrict__ part){
  const int t = threadIdx.x;
  const int wv = t>>6, lane = t&63;
  const int awave = blockIdx.x*256 + wv*64;
  const int split = blockIdx.y;
  const int j0 = split*JSPL;
  const int lg = lane>>4, ln = lane&15;

  // anchor B-fragments: B[k][n]; lane: n=ln, k=kk*32+lg*8+e
  short8v bf[4][4];
  #pragma unroll
  for (int ss = 0; ss < 4; ss++){
    const unsigned short* zr = zbf + (size_t)(awave + ss*16 + ln)*WD;
    #pragma unroll
    for (int kk = 0; kk < 4; kk++)
      bf[ss][kk] = *(const short8v*)(zr + kk*32 + lg*8);
  }

  float m[4], l[4];
  #pragma unroll
  for (int ss = 0; ss < 4; ss++){ m[ss] = -INFINITY; l[ss] = 0.f; }

  const unsigned short* ap = zbf + (size_t)(j0+ln)*WD + lg*8;
  short8v afA[4], afB[4];
#define LOADA(dst, tt) { const unsigned short* p_ = ap + (size_t)(tt)*16*WD; \
    dst[0] = *(const short8v*)(p_);      dst[1] = *(const short8v*)(p_+32);  \
    dst[2] = *(const short8v*)(p_+64);   dst[3] = *(const short8v*)(p_+96); }

#define COMPUTE(af, tt) { \
    const int jb = j0 + (tt)*16; \
    _Pragma("unroll") \
    for (int ss = 0; ss < 4; ss++){ \
      float4v acc = {0.f,0.f,0.f,0.f}; \
      __builtin_amdgcn_s_setprio(1); \
      _Pragma("unroll") \
      for (int kk = 0; kk < 4; kk++) \
        acc = __builtin_amdgcn_mfma_f32_16x16x32_bf16(af[kk], bf[ss][kk], acc, 0,0,0); \
      __builtin_amdgcn_s_setprio(0); \
      float v0 = acc[0], v1 = acc[1], v2 = acc[2], v3 = acc[3]; \
      if (jb == awave + ss*16){ \
        int r0 = lg*4; \
        if (r0+0 == ln) v0 = -INFINITY; \
        if (r0+1 == ln) v1 = -INFINITY; \
        if (r0+2 == ln) v2 = -INFINITY; \
        if (r0+3 == ln) v3 = -INFINITY; \
      } \
      float tmax = fmaxf(fmaxf(v0,v1), fmaxf(v2,v3)); \
      float mn = fmaxf(m[ss], tmax); \
      l[ss] = l[ss]*EXP2(m[ss]-mn) \
            + ((EXP2(v0-mn) + EXP2(v1-mn)) + (EXP2(v2-mn) + EXP2(v3-mn))); \
      m[ss] = mn; \
    } }

  LOADA(afA, 0);
  for (int tt = 0; tt < NTT; tt += 2){
    LOADA(afB, tt+1);
    COMPUTE(afA, tt);
    if (tt+2 < NTT) LOADA(afA, tt+2);
    COMPUTE(afB, tt+1);
  }
#undef LOADA
#undef COMPUTE

  // combine lanes {x^16, x^32} (same anchor, different j-rows)
  #pragma unroll
  for (int ss = 0; ss < 4; ss++){
    float mm = m[ss], ll = l[ss];
    #pragma unroll
    for (int off = 16; off < 64; off <<= 1){
      float mo = __shfl_xor(mm, off);
      float lo = __shfl_xor(ll, off);
      float M = fmaxf(mm, mo);
      ll = ll*EXP2(mm-M) + lo*EXP2(mo-M);
      mm = M;
    }
    if (lane < 16)
      part[(size_t)split*WB + awave + ss*16 + lane] = make_float2(mm, ll);
  }
}

// 256 blocks x 256 threads: 32 anchors/block, 8 threads per anchor.
__global__ __launch_bounds__(256) void k_final(const float* __restrict__ z,
                                               const int* __restrict__ labels,
                                               const float* __restrict__ S,
                                               const int* __restrict__ cnt,
                                               const float2* __restrict__ part,
                                               float* accf, int* accn, int* ticket,
                                               float* __restrict__ out){
  const int t = threadIdx.x;
  const int a = blockIdx.x*32 + (t>>3);   // anchor
  const int sub = t & 7;                  // 8 threads per anchor
  // max over this thread's 8 splits, then 8-lane reduce
  float mm = -INFINITY;
  #pragma unroll
  for (int k = 0; k < 8; k++)
    mm = fmaxf(mm, part[(size_t)(sub + 8*k)*WB + a].x);
  #pragma unroll
  for (int off = 1; off < 8; off <<= 1) mm = fmaxf(mm, __shfl_xor(mm, off));
  // exp-sum with fixed max
  float ll = 0.f;
  #pragma unroll
  for (int k = 0; k < 8; k++){
    float2 p = part[(size_t)(sub + 8*k)*WB + a];
    ll = fmaf(p.y, EXP2(p.x - mm), ll);
  }
  #pragma unroll
  for (int off = 1; off < 8; off <<= 1) ll += __shfl_xor(ll, off);
  float lse = (mm + LOG2(ll)) * LN2F;     // natural-log LSE
  int lab = labels[a];
  // dot over 16 cols per thread
  const float4* zi = (const float4*)(z + (size_t)a*WD + sub*16);
  const float4* sc = (const float4*)(S + (size_t)lab*WD + sub*16);
  float pd = 0.f, sd = 0.f;
  #pragma unroll
  for (int k = 0; k < 4; k++){
    float4 va = zi[k], vb = sc[k];
    pd += va.x*vb.x + va.y*vb.y + va.z*vb.z + va.w*vb.w;
    sd += va.x*va.x + va.y*va.y + va.z*va.z + va.w*va.w;
  }
  #pragma unroll
  for (int off = 1; off < 8; off <<= 1){
    pd += __shfl_xor(pd, off);
    sd += __shfl_xor(sd, off);
  }
  __shared__ float bl, bv;
  if (t == 0){ bl = 0.f; bv = 0.f; }
  __syncthreads();
  if (sub == 0){
    int np = cnt[lab] - 1;
    if (np > 0){
      float loss = lse - (pd - sd)*10.0f/(float)np;
      atomicAdd(&bl, loss);
      atomicAdd(&bv, 1.f);
    }
  }
  __syncthreads();
  if (t == 0){
    atomicAdd(accf, bl);
    atomicAdd(accn, (int)(bv + 0.5f));
    __threadfence();
    int tk = atomicAdd(ticket, 1);
    if (tk == 255){                        // last block finalizes
      float f = atomicAdd(accf, 0.f);
      int   n = atomicAdd(accn, 0);
      out[0] = f / (float)max(n, 1);
    }
  }
}

extern "C" void kernel_launch(void* const* d_in, const int* in_sizes, int n_in,
                              void* d_out, int out_size, void* d_ws, size_t ws_size,
                              hipStream_t stream){
  const float* z = (const float*)d_in[0];
  const int* labels = (const int*)d_in[1];
  char* ws = (char*)d_ws;
  unsigned short* zbf = (unsigned short*)(ws + WS_ZBF);
  float* S      = (float*)(ws + WS_S);
  int*   cnt    = (int*)(ws + WS_CNT);
  float* accf   = (float*)(ws + WS_ACC);
  int*   accn   = (int*)(ws + WS_ACC + 4);
  int*   ticket = (int*)(ws + WS_ACC + 8);
  float2* part  = (float2*)(ws + WS_PART);
  float* out = (float*)d_out;

  // zero S + cnt + acc in one contiguous async memset (graph-capturable)
  hipMemsetAsync(ws + WS_S, 0, (WS_ACC + 12) - WS_S, stream);
  hipLaunchKernelGGL(k_prep,  dim3(512 + 256),      dim3(256), 0, stream,
                     z, labels, zbf, S, cnt);
  hipLaunchKernelGGL(k_lse,   dim3(WB/256, NSPLIT), dim3(256), 0, stream, zbf, part);
  hipLaunchKernelGGL(k_final, dim3(256),            dim3(256), 0, stream,
                     z, labels, S, cnt, part, accf, accn, ticket, out);
}